// Round 6
// baseline (145.400 us; speedup 1.0000x reference)
//
#include <hip/hip_runtime.h>

// MaskLayer: inputs [B=512, H=14, W=14, C=512] fp32, channel-innermost.
// Identity: rows_idx = min{h : x[b,h,w,c]==M}, cols_idx = min{w : ...==M},
// M = global max over (h,w). One (max, min-h, min-w) scan replaces both
// argmaxes (exact, incl. jnp.argmax first-occurrence tie rules).
//
// R5: full-linearity layout. lane = 64 consecutive channel-quads -> every
// global load/store instruction is ONE contiguous 1 KB segment; each wave
// owns 24-25 CONSECUTIVE positions (sequential ~50 KB region). Values are
// register-resident (single pass). No shuffles; cross-wave merge via 16 KB
// LDS laid out [j][wv][lane] (lane stride 4 B -> conflict-free).
// Grid: 512 samples x 2 channel-halves = 1024 blocks x 512 threads (8 waves).

typedef float f32x4 __attribute__((ext_vector_type(4)));

#define IMG  14
#define NPOS 196
#define Q    128   // float4 quads per position (512 ch / 4)

__global__ __launch_bounds__(512, 4)
void mask_kernel(const f32x4* __restrict__ in, f32x4* __restrict__ out) {
    const int b     = blockIdx.x >> 1;
    const int qhalf = blockIdx.x & 1;
    const int lane  = threadIdx.x & 63;
    const int wv    = threadIdx.x >> 6;          // 8 position groups
    const int quad  = (qhalf << 6) | lane;       // 64 consecutive quads/wave

    const bool big   = wv < 4;                   // 25-position groups
    const int  start = big ? wv * 25 : 100 + (wv - 4) * 24;

    const f32x4* __restrict__ bin  = in  + (size_t)b * (NPOS * Q) + quad;
    f32x4*       __restrict__ bout = out + (size_t)b * (NPOS * Q) + quad;

    // ---- issue all loads back-to-back (independent addresses) ----
    f32x4 v[24];
#pragma unroll
    for (int k = 0; k < 24; ++k)
        v[k] = bin[(size_t)(start + k) * Q];
    f32x4 v24;
    if (big) v24 = bin[(size_t)(start + 24) * Q];

    // ---- scan from registers: (max, min-h@max, min-w@max) per channel ----
    const int h0 = start / IMG;
    const int w0 = start - h0 * IMG;
    float m[4]; int hi[4], wi[4];
#pragma unroll
    for (int j = 0; j < 4; ++j) { m[j] = v[0][j]; hi[j] = h0; wi[j] = w0; }
    int h = h0, w = w0;
#pragma unroll
    for (int k = 1; k < 24; ++k) {
        ++w; if (w == IMG) { w = 0; ++h; }
#pragma unroll
        for (int j = 0; j < 4; ++j) {
            float x = v[k][j];
            bool gt = x > m[j];
            bool eq = x == m[j];
            m[j]  = gt ? x : m[j];
            hi[j] = gt ? h : hi[j];              // h ascending: eq keeps min
            int wmn = wi[j] < w ? wi[j] : w;
            wi[j] = gt ? w : (eq ? wmn : wi[j]);
        }
    }
    {   // 25th position (big groups only)
        int h24 = h, w24 = w;
        ++w24; if (w24 == IMG) { w24 = 0; ++h24; }
        if (big) {
#pragma unroll
            for (int j = 0; j < 4; ++j) {
                float x = v24[j];
                bool gt = x > m[j];
                bool eq = x == m[j];
                m[j]  = gt ? x : m[j];
                hi[j] = gt ? h24 : hi[j];
                int wmn = wi[j] < w24 ? wi[j] : w24;
                wi[j] = gt ? w24 : (eq ? wmn : wi[j]);
            }
        }
    }

    // ---- cross-wave merge via LDS; [j][wv][lane] -> lane stride 4 B ----
    __shared__ float lm[4][8][64];
    __shared__ int   lp[4][8][64];
#pragma unroll
    for (int j = 0; j < 4; ++j) {
        lm[j][wv][lane] = m[j];
        lp[j][wv][lane] = (hi[j] << 8) | wi[j];
    }
    __syncthreads();
#pragma unroll
    for (int ov = 0; ov < 8; ++ov) {
#pragma unroll
        for (int j = 0; j < 4; ++j) {
            float om = lm[j][ov][lane];
            int   op = lp[j][ov][lane];
            int   oh = op >> 8, ow = op & 255;
            if (om > m[j]) { m[j] = om; hi[j] = oh; wi[j] = ow; }
            else if (om == m[j]) {
                hi[j] = hi[j] < oh ? hi[j] : oh;
                wi[j] = wi[j] < ow ? wi[j] : ow;
            }
        }
    }

    // ---- mask + store straight from registers (sequential 1 KB lines) ----
    const float kk  = (float)(4.0 / 14.0);          // BETA / IMG
    const float tau = (float)(0.5 / (14.0 * 14.0)); // TAU
    h = h0; w = w0;
#pragma unroll
    for (int k = 0; k < 24; ++k) {
        if (k) { ++w; if (w == IMG) { w = 0; ++h; } }
        f32x4 o;
#pragma unroll
        for (int j = 0; j < 4; ++j) {
            int dh = h - hi[j]; dh = dh < 0 ? -dh : dh;
            int dw = w - wi[j]; dw = dw < 0 ? -dw : dw;
            float wt = fmaxf(1.0f - kk * (float)(dh + dw), -1.0f) * tau;
            o[j] = fmaxf(wt * v[k][j], 0.0f);
        }
        __builtin_nontemporal_store(o, &bout[(size_t)(start + k) * Q]);
    }
    {
        ++w; if (w == IMG) { w = 0; ++h; }
        if (big) {
            f32x4 o;
#pragma unroll
            for (int j = 0; j < 4; ++j) {
                int dh = h - hi[j]; dh = dh < 0 ? -dh : dh;
                int dw = w - wi[j]; dw = dw < 0 ? -dw : dw;
                float wt = fmaxf(1.0f - kk * (float)(dh + dw), -1.0f) * tau;
                o[j] = fmaxf(wt * v24[j], 0.0f);
            }
            __builtin_nontemporal_store(o, &bout[(size_t)(start + 24) * Q]);
        }
    }
}

extern "C" void kernel_launch(void* const* d_in, const int* in_sizes, int n_in,
                              void* d_out, int out_size, void* d_ws, size_t ws_size,
                              hipStream_t stream) {
    const f32x4* in  = (const f32x4*)d_in[0];
    f32x4*       out = (f32x4*)d_out;
    // 512 samples x 2 channel-halves; 512 thr = 8 waves x 64 quads
    mask_kernel<<<512 * 2, 512, 0, stream>>>(in, out);
}

// Round 7
// 93.979 us; speedup vs baseline: 1.5472x; 1.5472x over previous
//
#include <hip/hip_runtime.h>

// MaskLayer: inputs [B=512, H=14, W=14, C=512] fp32, channel-innermost.
// Identity: rows_idx = min{h : x[b,h,w,c]==M}, cols_idx = min{w : ...==M}
// (independent mins over the set of positions attaining the global max M) —
// exactly reproduces both jnp.argmax first-occurrence results.
//
// Single-pass, register-resident, SPILL-FREE sizing:
//   * 12-13 f32x4 live per thread (~52 data VGPRs); __launch_bounds__(512,2)
//     relaxes the compiler's occupancy target so it allocates ~100 VGPRs
//     instead of pinning 64 and spilling (R4/R5 lesson: spill = hidden
//     scratch traffic, showed up as FETCH/WRITE amplification).
//   * lane = psub*32 + q32 -> each half-wave = 32 consecutive float4-quads
//     = 512 B contiguous per load/store instruction; each position-group is
//     a consecutive ~25 KB region.
//   * merge: __shfl_xor(32) across psub, then 8-way LDS exchange (8 KB).
// Grid: 512 samples x 4 quad-blocks = 2048 blocks x 512 threads (8 waves).

typedef float f32x4 __attribute__((ext_vector_type(4)));

#define IMG  14
#define NPOS 196
#define Q    128   // float4 quads per position (512 ch / 4)

__global__ __launch_bounds__(512, 2)
void mask_kernel(const f32x4* __restrict__ in, f32x4* __restrict__ out) {
    const int b    = blockIdx.x >> 2;
    const int qblk = blockIdx.x & 3;
    const int lane = threadIdx.x & 63;
    const int wv   = threadIdx.x >> 6;        // wave 0..7
    const int q32  = lane & 31;               // quad within 32-quad chunk
    const int psub = lane >> 5;               // position subgroup 0..1
    const int g    = wv * 2 + psub;           // 16 position-groups
    const int quad = qblk * 32 + q32;         // channel quad

    const bool big   = g < 4;                 // 13-position groups
    const int  start = big ? g * 13 : 52 + (g - 4) * 12;

    const f32x4* __restrict__ bin  = in  + (size_t)b * (NPOS * Q) + quad;
    f32x4*       __restrict__ bout = out + (size_t)b * (NPOS * Q) + quad;

    // ---- issue all loads back-to-back (independent addresses) ----
    f32x4 v[12];
#pragma unroll
    for (int k = 0; k < 12; ++k)
        v[k] = bin[(size_t)(start + k) * Q];
    f32x4 v12;
    if (big) v12 = bin[(size_t)(start + 12) * Q];

    // ---- scan from registers: (max, min-h@max, min-w@max) per channel ----
    const int h0 = start / IMG;
    const int w0 = start - h0 * IMG;
    float m[4]; int hi[4], wi[4];
#pragma unroll
    for (int j = 0; j < 4; ++j) { m[j] = v[0][j]; hi[j] = h0; wi[j] = w0; }
    int h = h0, w = w0;
#pragma unroll
    for (int k = 1; k < 12; ++k) {
        ++w; if (w == IMG) { w = 0; ++h; }
#pragma unroll
        for (int j = 0; j < 4; ++j) {
            float x = v[k][j];
            bool gt = x > m[j];
            bool eq = x == m[j];
            m[j]  = gt ? x : m[j];
            hi[j] = gt ? h : hi[j];            // h ascending: eq keeps min
            int wmn = wi[j] < w ? wi[j] : w;
            wi[j] = gt ? w : (eq ? wmn : wi[j]);
        }
    }
    {   // 13th position (big groups only)
        int h12 = h, w12 = w;
        ++w12; if (w12 == IMG) { w12 = 0; ++h12; }
        if (big) {
#pragma unroll
            for (int j = 0; j < 4; ++j) {
                float x = v12[j];
                bool gt = x > m[j];
                bool eq = x == m[j];
                m[j]  = gt ? x : m[j];
                hi[j] = gt ? h12 : hi[j];
                int wmn = wi[j] < w12 ? wi[j] : w12;
                wi[j] = gt ? w12 : (eq ? wmn : wi[j]);
            }
        }
    }

    // ---- merge across the 2 psubs (same q32): xor 32 ----
#pragma unroll
    for (int j = 0; j < 4; ++j) {
        float om = __shfl_xor(m[j], 32, 64);
        int   oh = __shfl_xor(hi[j], 32, 64);
        int   ow = __shfl_xor(wi[j], 32, 64);
        if (om > m[j]) { m[j] = om; hi[j] = oh; wi[j] = ow; }
        else if (om == m[j]) {
            hi[j] = hi[j] < oh ? hi[j] : oh;
            wi[j] = wi[j] < ow ? wi[j] : ow;
        }
    }

    // ---- merge across the 8 waves via LDS (idempotent re-merge) ----
    __shared__ float lm[4][8][32];
    __shared__ int   lp[4][8][32];
    if (psub == 0) {
#pragma unroll
        for (int j = 0; j < 4; ++j) {
            lm[j][wv][q32] = m[j];
            lp[j][wv][q32] = (hi[j] << 8) | wi[j];
        }
    }
    __syncthreads();
#pragma unroll
    for (int ov = 0; ov < 8; ++ov) {
#pragma unroll
        for (int j = 0; j < 4; ++j) {
            float om = lm[j][ov][q32];
            int   op = lp[j][ov][q32];
            int   oh = op >> 8, ow = op & 255;
            if (om > m[j]) { m[j] = om; hi[j] = oh; wi[j] = ow; }
            else if (om == m[j]) {
                hi[j] = hi[j] < oh ? hi[j] : oh;
                wi[j] = wi[j] < ow ? wi[j] : ow;
            }
        }
    }

    // ---- mask + store straight from registers (512 B chunks, NT) ----
    const float kk  = (float)(4.0 / 14.0);          // BETA / IMG
    const float tau = (float)(0.5 / (14.0 * 14.0)); // TAU
    h = h0; w = w0;
#pragma unroll
    for (int k = 0; k < 12; ++k) {
        if (k) { ++w; if (w == IMG) { w = 0; ++h; } }
        f32x4 o;
#pragma unroll
        for (int j = 0; j < 4; ++j) {
            int dh = h - hi[j]; dh = dh < 0 ? -dh : dh;
            int dw = w - wi[j]; dw = dw < 0 ? -dw : dw;
            float wt = fmaxf(1.0f - kk * (float)(dh + dw), -1.0f) * tau;
            o[j] = fmaxf(wt * v[k][j], 0.0f);
        }
        __builtin_nontemporal_store(o, &bout[(size_t)(start + k) * Q]);
    }
    {
        ++w; if (w == IMG) { w = 0; ++h; }
        if (big) {
            f32x4 o;
#pragma unroll
            for (int j = 0; j < 4; ++j) {
                int dh = h - hi[j]; dh = dh < 0 ? -dh : dh;
                int dw = w - wi[j]; dw = dw < 0 ? -dw : dw;
                float wt = fmaxf(1.0f - kk * (float)(dh + dw), -1.0f) * tau;
                o[j] = fmaxf(wt * v12[j], 0.0f);
            }
            __builtin_nontemporal_store(o, &bout[(size_t)(start + 12) * Q]);
        }
    }
}

extern "C" void kernel_launch(void* const* d_in, const int* in_sizes, int n_in,
                              void* d_out, int out_size, void* d_ws, size_t ws_size,
                              hipStream_t stream) {
    const f32x4* in  = (const f32x4*)d_in[0];
    f32x4*       out = (f32x4*)d_out;
    // 512 samples x 4 quad-blocks; 512 thr = 8 waves x (2 psub x 32 quads)
    mask_kernel<<<512 * 4, 512, 0, stream>>>(in, out);
}

// Round 8
// 65.914 us; speedup vs baseline: 2.2059x; 1.4258x over previous
//
#include <hip/hip_runtime.h>

// MaskLayer: inputs [B=512, H=14, W=14, C=512] fp32, channel-innermost.
// Identity: rows_idx = min{h : x[b,h,w,c]==M}, cols_idx = min{w : ...==M}
// (independent mins over positions attaining the global max M) — exactly
// reproduces both jnp.argmax first-occurrence results.
//
// R7: occupancy-first sizing. Latency-bound op -> maximize resident waves.
//   * 6-7 f32x4 live per thread (24-28 data VGPRs, ~56 total, no spill)
//     -> 8 waves/EU possible (32 waves/CU, ~3x R6).
//   * 32 position-groups (4x7 + 28x6) = 4 waves x 8 psubs; lane = psub*8+q8
//     -> every load/store instr = 8 consecutive quads = 128 B full lines
//     (R2 proved 128 B chunks have zero write amplification).
//   * merge: __shfl_xor(8/16/32) across psubs + tiny LDS across 4 waves.
// Grid: 512 samples x 16 quad-blocks = 8192 blocks x 256 threads.

typedef float f32x4 __attribute__((ext_vector_type(4)));

#define IMG  14
#define NPOS 196
#define Q    128   // float4 quads per position (512 ch / 4)

__global__ __launch_bounds__(256, 4)
void mask_kernel(const f32x4* __restrict__ in, f32x4* __restrict__ out) {
    const int b    = blockIdx.x >> 4;
    const int qblk = blockIdx.x & 15;
    const int lane = threadIdx.x & 63;
    const int wv   = threadIdx.x >> 6;        // wave 0..3
    const int q8   = lane & 7;                // quad within 8-quad chunk
    const int psub = lane >> 3;               // position subgroup 0..7
    const int g    = wv * 8 + psub;           // 32 position-groups
    const int quad = qblk * 8 + q8;           // channel quad

    const bool big   = g < 4;                 // 7-position groups
    const int  start = big ? g * 7 : 28 + (g - 4) * 6;

    const f32x4* __restrict__ bin  = in  + (size_t)b * (NPOS * Q) + quad;
    f32x4*       __restrict__ bout = out + (size_t)b * (NPOS * Q) + quad;

    // ---- issue all loads back-to-back (independent addresses) ----
    f32x4 v[6];
#pragma unroll
    for (int k = 0; k < 6; ++k)
        v[k] = bin[(size_t)(start + k) * Q];
    f32x4 v6;
    if (big) v6 = bin[(size_t)(start + 6) * Q];

    // ---- scan from registers: (max, min-h@max, min-w@max) per channel ----
    const int h0 = start / IMG;
    const int w0 = start - h0 * IMG;
    float m[4]; int hi[4], wi[4];
#pragma unroll
    for (int j = 0; j < 4; ++j) { m[j] = v[0][j]; hi[j] = h0; wi[j] = w0; }
    int h = h0, w = w0;
#pragma unroll
    for (int k = 1; k < 6; ++k) {
        ++w; if (w == IMG) { w = 0; ++h; }
#pragma unroll
        for (int j = 0; j < 4; ++j) {
            float x = v[k][j];
            bool gt = x > m[j];
            bool eq = x == m[j];
            m[j]  = gt ? x : m[j];
            hi[j] = gt ? h : hi[j];            // h ascending: eq keeps min
            int wmn = wi[j] < w ? wi[j] : w;
            wi[j] = gt ? w : (eq ? wmn : wi[j]);
        }
    }
    {   // 7th position (big groups only)
        int h6 = h, w6 = w;
        ++w6; if (w6 == IMG) { w6 = 0; ++h6; }
        if (big) {
#pragma unroll
            for (int j = 0; j < 4; ++j) {
                float x = v6[j];
                bool gt = x > m[j];
                bool eq = x == m[j];
                m[j]  = gt ? x : m[j];
                hi[j] = gt ? h6 : hi[j];
                int wmn = wi[j] < w6 ? wi[j] : w6;
                wi[j] = gt ? w6 : (eq ? wmn : wi[j]);
            }
        }
    }

    // ---- merge across the 8 psubs (lane bits 3-5): xor 8,16,32 ----
#pragma unroll
    for (int s = 8; s <= 32; s <<= 1) {
#pragma unroll
        for (int j = 0; j < 4; ++j) {
            float om = __shfl_xor(m[j], s, 64);
            int   oh = __shfl_xor(hi[j], s, 64);
            int   ow = __shfl_xor(wi[j], s, 64);
            if (om > m[j]) { m[j] = om; hi[j] = oh; wi[j] = ow; }
            else if (om == m[j]) {
                hi[j] = hi[j] < oh ? hi[j] : oh;
                wi[j] = wi[j] < ow ? wi[j] : ow;
            }
        }
    }

    // ---- merge across the 4 waves via LDS (idempotent re-merge) ----
    __shared__ float lm[4][4][8];   // [j][wv][q8]
    __shared__ int   lp[4][4][8];
    if (psub == 0) {
#pragma unroll
        for (int j = 0; j < 4; ++j) {
            lm[j][wv][q8] = m[j];
            lp[j][wv][q8] = (hi[j] << 8) | wi[j];
        }
    }
    __syncthreads();
#pragma unroll
    for (int ov = 0; ov < 4; ++ov) {
#pragma unroll
        for (int j = 0; j < 4; ++j) {
            float om = lm[j][ov][q8];       // same addr across psubs: broadcast
            int   op = lp[j][ov][q8];
            int   oh = op >> 8, ow = op & 255;
            if (om > m[j]) { m[j] = om; hi[j] = oh; wi[j] = ow; }
            else if (om == m[j]) {
                hi[j] = hi[j] < oh ? hi[j] : oh;
                wi[j] = wi[j] < ow ? wi[j] : ow;
            }
        }
    }

    // ---- mask + store straight from registers (128 B full lines, NT) ----
    const float kk  = (float)(4.0 / 14.0);          // BETA / IMG
    const float tau = (float)(0.5 / (14.0 * 14.0)); // TAU
    h = h0; w = w0;
#pragma unroll
    for (int k = 0; k < 6; ++k) {
        if (k) { ++w; if (w == IMG) { w = 0; ++h; } }
        f32x4 o;
#pragma unroll
        for (int j = 0; j < 4; ++j) {
            int dh = h - hi[j]; dh = dh < 0 ? -dh : dh;
            int dw = w - wi[j]; dw = dw < 0 ? -dw : dw;
            float wt = fmaxf(1.0f - kk * (float)(dh + dw), -1.0f) * tau;
            o[j] = fmaxf(wt * v[k][j], 0.0f);
        }
        __builtin_nontemporal_store(o, &bout[(size_t)(start + k) * Q]);
    }
    {
        ++w; if (w == IMG) { w = 0; ++h; }
        if (big) {
            f32x4 o;
#pragma unroll
            for (int j = 0; j < 4; ++j) {
                int dh = h - hi[j]; dh = dh < 0 ? -dh : dh;
                int dw = w - wi[j]; dw = dw < 0 ? -dw : dw;
                float wt = fmaxf(1.0f - kk * (float)(dh + dw), -1.0f) * tau;
                o[j] = fmaxf(wt * v6[j], 0.0f);
            }
            __builtin_nontemporal_store(o, &bout[(size_t)(start + 6) * Q]);
        }
    }
}

extern "C" void kernel_launch(void* const* d_in, const int* in_sizes, int n_in,
                              void* d_out, int out_size, void* d_ws, size_t ws_size,
                              hipStream_t stream) {
    const f32x4* in  = (const f32x4*)d_in[0];
    f32x4*       out = (f32x4*)d_out;
    // 512 samples x 16 quad-blocks; 256 thr = 4 waves x (8 psub x 8 quads)
    mask_kernel<<<512 * 16, 256, 0, stream>>>(in, out);
}